// Round 1
// baseline (743.280 us; speedup 1.0000x reference)
//
#include <hip/hip_runtime.h>
#include <hip/hip_bf16.h>

#define N_NODES 100000
#define N_EDGES 1600000
#define IN_DIM 256
#define HIDDEN 128
#define NCLS 40
#define SCAN_BLOCKS 98   // ceil(100000/1024)

// ---------------- CSR build ----------------

__global__ void k_count(const int* __restrict__ dst, int* __restrict__ cnt) {
    int e = blockIdx.x * 256 + threadIdx.x;
    if (e < N_EDGES) atomicAdd(&cnt[dst[e]], 1);
}

__global__ void k_scanA(const int* __restrict__ cnt, int* __restrict__ tmp, int* __restrict__ bsum) {
    int i = blockIdx.x * 1024 + threadIdx.x;
    int v = (i < N_NODES) ? cnt[i] : 0;
    int lane = threadIdx.x & 63;
    int wid  = threadIdx.x >> 6;   // 0..15
    // wave-64 inclusive scan
    #pragma unroll
    for (int d = 1; d < 64; d <<= 1) {
        int u = __shfl_up(v, d, 64);
        if (lane >= d) v += u;
    }
    __shared__ int ws[16];
    if (lane == 63) ws[wid] = v;
    __syncthreads();
    if (wid == 0) {
        int s = (lane < 16) ? ws[lane] : 0;
        #pragma unroll
        for (int d = 1; d < 16; d <<= 1) {
            int u = __shfl_up(s, d, 64);
            if (lane >= d) s += u;
        }
        if (lane < 16) ws[lane] = s;
    }
    __syncthreads();
    if (wid > 0) v += ws[wid - 1];
    if (i < N_NODES) tmp[i] = v;
    if (threadIdx.x == 1023) bsum[blockIdx.x] = v;
}

__global__ void k_scanB(const int* __restrict__ bsum, int* __restrict__ boff, int* __restrict__ row_ptr) {
    if (threadIdx.x == 0 && blockIdx.x == 0) {
        int run = 0;
        for (int b = 0; b < SCAN_BLOCKS; b++) { boff[b] = run; run += bsum[b]; }
        row_ptr[N_NODES] = run;   // == N_EDGES
    }
}

__global__ void k_scanC(const int* __restrict__ tmp, const int* __restrict__ cnt,
                        const int* __restrict__ boff, int* __restrict__ row_ptr) {
    int i = blockIdx.x * 256 + threadIdx.x;
    if (i < N_NODES) row_ptr[i] = boff[i >> 10] + tmp[i] - cnt[i];   // exclusive
}

__global__ void k_scatter(const int* __restrict__ src, const int* __restrict__ dst,
                          const int* __restrict__ row_ptr, int* __restrict__ fill,
                          int* __restrict__ col) {
    int e = blockIdx.x * 256 + threadIdx.x;
    if (e < N_EDGES) {
        int d = dst[e];
        int pos = row_ptr[d] + atomicAdd(&fill[d], 1);
        col[pos] = src[e];
    }
}

__global__ void k_dinv(const int* __restrict__ cnt, float* __restrict__ dinv) {
    int i = blockIdx.x * 256 + threadIdx.x;
    if (i < N_NODES) dinv[i] = rsqrtf((float)(cnt[i] + 1));   // +1 self-loop; always > 0
}

// ---------------- GEMM1: H1 = X @ W1  (100000x256 @ 256x128, fp32) ----------------
// 64x128 tile, 256 threads, each thread 4x8 micro-tile, BK=16, A stored transposed in LDS.

__global__ __launch_bounds__(256) void k_gemm1(const float* __restrict__ X,
                                               const float* __restrict__ W,
                                               float* __restrict__ H) {
    __shared__ __align__(16) float As[16][68];    // [k][m], padded
    __shared__ __align__(16) float Bs[16][132];   // [k][n], padded
    const int tid = threadIdx.x;
    const int tx = tid & 15;    // col group -> 8 cols
    const int ty = tid >> 4;    // row group -> 4 rows
    const int row0 = blockIdx.x * 64;

    float acc[4][8];
    #pragma unroll
    for (int r = 0; r < 4; r++)
        #pragma unroll
        for (int c = 0; c < 8; c++) acc[r][c] = 0.f;

    const int lr = tid >> 2;          // 0..63 : A load row
    const int lk = (tid & 3) * 4;     // k quad

    for (int k0 = 0; k0 < IN_DIM; k0 += 16) {
        // stage A (64 rows x 16 k), transposed into LDS
        float4 a = make_float4(0.f, 0.f, 0.f, 0.f);
        int gr = row0 + lr;
        if (gr < N_NODES) a = *(const float4*)&X[(long)gr * IN_DIM + k0 + lk];
        As[lk + 0][lr] = a.x; As[lk + 1][lr] = a.y; As[lk + 2][lr] = a.z; As[lk + 3][lr] = a.w;
        // stage B (16 k x 128 n): 512 float4 / 256 threads = 2 each
        {
            int idx = tid;
            int kk = idx >> 5, c4 = (idx & 31) * 4;
            *(float4*)&Bs[kk][c4] = *(const float4*)&W[(k0 + kk) * HIDDEN + c4];
            idx = tid + 256;
            kk = idx >> 5; c4 = (idx & 31) * 4;
            *(float4*)&Bs[kk][c4] = *(const float4*)&W[(k0 + kk) * HIDDEN + c4];
        }
        __syncthreads();
        #pragma unroll
        for (int kk = 0; kk < 16; kk++) {
            float4 av = *(const float4*)&As[kk][ty * 4];
            float4 b0 = *(const float4*)&Bs[kk][tx * 8];
            float4 b1 = *(const float4*)&Bs[kk][tx * 8 + 4];
            float a_[4] = {av.x, av.y, av.z, av.w};
            float b_[8] = {b0.x, b0.y, b0.z, b0.w, b1.x, b1.y, b1.z, b1.w};
            #pragma unroll
            for (int r = 0; r < 4; r++)
                #pragma unroll
                for (int c = 0; c < 8; c++) acc[r][c] += a_[r] * b_[c];
        }
        __syncthreads();
    }
    #pragma unroll
    for (int r = 0; r < 4; r++) {
        int gr = row0 + ty * 4 + r;
        if (gr < N_NODES) {
            float4 o0 = make_float4(acc[r][0], acc[r][1], acc[r][2], acc[r][3]);
            float4 o1 = make_float4(acc[r][4], acc[r][5], acc[r][6], acc[r][7]);
            *(float4*)&H[(long)gr * HIDDEN + tx * 8]     = o0;
            *(float4*)&H[(long)gr * HIDDEN + tx * 8 + 4] = o1;
        }
    }
}

// ---------------- Aggregation 1 (+bias+ReLU): H1a[d] = relu(dinv[d]*(sum dinv[s]*H1[s] + dinv[d]*H1[d]) + b1) ----

__global__ __launch_bounds__(256) void k_agg1(const float* __restrict__ H1,
                                              const int* __restrict__ row_ptr,
                                              const int* __restrict__ col,
                                              const float* __restrict__ dinv,
                                              const float* __restrict__ b1,
                                              float* __restrict__ H1a) {
    int d = blockIdx.x * 2 + (threadIdx.x >> 7);   // 2 nodes per block
    int f = threadIdx.x & 127;
    int e0 = row_ptr[d], e1 = row_ptr[d + 1];
    float acc = 0.f;
    int e = e0;
    for (; e + 1 < e1; e += 2) {
        int sa = col[e], sb = col[e + 1];
        float da = dinv[sa], db = dinv[sb];
        float ha = H1[(long)sa * HIDDEN + f];
        float hb = H1[(long)sb * HIDDEN + f];
        acc += da * ha;
        acc += db * hb;
    }
    if (e < e1) {
        int sa = col[e];
        acc += dinv[sa] * H1[(long)sa * HIDDEN + f];
    }
    float dd = dinv[d];
    float out = dd * (acc + dd * H1[(long)d * HIDDEN + f]) + b1[f];
    H1a[(long)d * HIDDEN + f] = fmaxf(out, 0.f);
}

// ---------------- GEMM2: H2 = H1a @ W2 (100000x128 @ 128x40), W2 in LDS ----------------

__global__ __launch_bounds__(256) void k_gemm2(const float* __restrict__ H1a,
                                               const float* __restrict__ W2,
                                               float* __restrict__ H2) {
    __shared__ float Ws[HIDDEN * NCLS];   // 20 KB
    for (int i = threadIdx.x; i < HIDDEN * NCLS; i += 256) Ws[i] = W2[i];
    __syncthreads();
    long gid = (long)blockIdx.x * 256 + threadIdx.x;
    if (gid >= (long)N_NODES * NCLS) return;
    int row = (int)(gid / NCLS);
    int c   = (int)(gid - (long)row * NCLS);
    const float* hrow = &H1a[(long)row * HIDDEN];
    float acc = 0.f;
    #pragma unroll
    for (int k4 = 0; k4 < HIDDEN / 4; k4++) {
        float4 h = *(const float4*)&hrow[k4 * 4];
        acc += h.x * Ws[(k4 * 4 + 0) * NCLS + c];
        acc += h.y * Ws[(k4 * 4 + 1) * NCLS + c];
        acc += h.z * Ws[(k4 * 4 + 2) * NCLS + c];
        acc += h.w * Ws[(k4 * 4 + 3) * NCLS + c];
    }
    H2[gid] = acc;
}

// ---------------- Aggregation 2 (+bias): out = dinv[d]*(sum dinv[s]*H2[s] + dinv[d]*H2[d]) + b2 ----

__global__ __launch_bounds__(256) void k_agg2(const float* __restrict__ H2,
                                              const int* __restrict__ row_ptr,
                                              const int* __restrict__ col,
                                              const float* __restrict__ dinv,
                                              const float* __restrict__ b2,
                                              float* __restrict__ out) {
    int d = blockIdx.x * 4 + (threadIdx.x >> 6);   // 4 nodes per block (one wave each)
    int f = threadIdx.x & 63;
    if (f >= NCLS) return;
    int e0 = row_ptr[d], e1 = row_ptr[d + 1];
    float acc = 0.f;
    int e = e0;
    for (; e + 1 < e1; e += 2) {
        int sa = col[e], sb = col[e + 1];
        float da = dinv[sa], db = dinv[sb];
        float ha = H2[(long)sa * NCLS + f];
        float hb = H2[(long)sb * NCLS + f];
        acc += da * ha;
        acc += db * hb;
    }
    if (e < e1) {
        int sa = col[e];
        acc += dinv[sa] * H2[(long)sa * NCLS + f];
    }
    float dd = dinv[d];
    out[(long)d * NCLS + f] = dd * (acc + dd * H2[(long)d * NCLS + f]) + b2[f];
}

// ---------------- launch ----------------

extern "C" void kernel_launch(void* const* d_in, const int* in_sizes, int n_in,
                              void* d_out, int out_size, void* d_ws, size_t ws_size,
                              hipStream_t stream) {
    const float* x  = (const float*)d_in[0];
    const int*   ei = (const int*)d_in[1];      // int32 (JAX default, x64 disabled)
    const float* W1 = (const float*)d_in[2];
    const float* b1 = (const float*)d_in[3];
    const float* W2 = (const float*)d_in[4];
    const float* b2 = (const float*)d_in[5];
    const int* srcE = ei;
    const int* dstE = ei + N_EDGES;

    // workspace layout (ints are 128-element padded for alignment)
    int*   cnt     = (int*)d_ws;                 // 100000
    int*   row_ptr = cnt + 100032;               // 100001
    int*   fill    = row_ptr + 100032;           // 100000
    int*   boff    = fill + 100032;              // 128
    int*   tmp     = boff + 128;                 // 100000
    int*   bsum    = tmp + 100032;               // 128
    int*   col     = bsum + 128;                 // 1600000
    float* dinv    = (float*)(col + N_EDGES);    // 100000
    float* H1      = dinv + 100032;              // 12.8M floats
    float* H1a     = H1 + (long)N_NODES * HIDDEN;// 12.8M floats
    float* H2      = H1;                         // reuse H1 (free after agg1)

    hipMemsetAsync(cnt,  0, N_NODES * sizeof(int), stream);
    hipMemsetAsync(fill, 0, N_NODES * sizeof(int), stream);

    k_count  <<<(N_EDGES + 255) / 256, 256, 0, stream>>>(dstE, cnt);
    k_scanA  <<<SCAN_BLOCKS, 1024, 0, stream>>>(cnt, tmp, bsum);
    k_scanB  <<<1, 64, 0, stream>>>(bsum, boff, row_ptr);
    k_scanC  <<<(N_NODES + 255) / 256, 256, 0, stream>>>(tmp, cnt, boff, row_ptr);
    k_scatter<<<(N_EDGES + 255) / 256, 256, 0, stream>>>(srcE, dstE, row_ptr, fill, col);
    k_dinv   <<<(N_NODES + 255) / 256, 256, 0, stream>>>(cnt, dinv);

    k_gemm1  <<<(N_NODES + 63) / 64, 256, 0, stream>>>(x, W1, H1);
    k_agg1   <<<N_NODES / 2, 256, 0, stream>>>(H1, row_ptr, col, dinv, b1, H1a);
    k_gemm2  <<<(int)(((long)N_NODES * NCLS + 255) / 256), 256, 0, stream>>>(H1a, W2, H2);
    k_agg2   <<<N_NODES / 4, 256, 0, stream>>>(H2, row_ptr, col, dinv, b2, (float*)d_out);
}

// Round 2
// 578.595 us; speedup vs baseline: 1.2846x; 1.2846x over previous
//
#include <hip/hip_runtime.h>
#include <hip/hip_bf16.h>
#include <hip/hip_fp16.h>

#define N_NODES 100000
#define N_EDGES 1600000
#define IN_DIM 256
#define HIDDEN 128
#define NCLS 40
#define SCAN_BLOCKS 98   // ceil(100000/1024)

// ---------------- CSR build ----------------

__global__ void k_count(const int* __restrict__ dst, int* __restrict__ cnt) {
    int e = blockIdx.x * 256 + threadIdx.x;
    if (e < N_EDGES) atomicAdd(&cnt[dst[e]], 1);
}

__global__ void k_scanA(const int* __restrict__ cnt, int* __restrict__ tmp, int* __restrict__ bsum) {
    int i = blockIdx.x * 1024 + threadIdx.x;
    int v = (i < N_NODES) ? cnt[i] : 0;
    int lane = threadIdx.x & 63;
    int wid  = threadIdx.x >> 6;   // 0..15
    #pragma unroll
    for (int d = 1; d < 64; d <<= 1) {
        int u = __shfl_up(v, d, 64);
        if (lane >= d) v += u;
    }
    __shared__ int ws[16];
    if (lane == 63) ws[wid] = v;
    __syncthreads();
    if (wid == 0) {
        int s = (lane < 16) ? ws[lane] : 0;
        #pragma unroll
        for (int d = 1; d < 16; d <<= 1) {
            int u = __shfl_up(s, d, 64);
            if (lane >= d) s += u;
        }
        if (lane < 16) ws[lane] = s;
    }
    __syncthreads();
    if (wid > 0) v += ws[wid - 1];
    if (i < N_NODES) tmp[i] = v;
    if (threadIdx.x == 1023) bsum[blockIdx.x] = v;
}

__global__ void k_scanB(const int* __restrict__ bsum, int* __restrict__ boff, int* __restrict__ row_ptr) {
    if (threadIdx.x == 0 && blockIdx.x == 0) {
        int run = 0;
        for (int b = 0; b < SCAN_BLOCKS; b++) { boff[b] = run; run += bsum[b]; }
        row_ptr[N_NODES] = run;   // == N_EDGES
    }
}

__global__ void k_scanC(const int* __restrict__ tmp, const int* __restrict__ cnt,
                        const int* __restrict__ boff, int* __restrict__ row_ptr) {
    int i = blockIdx.x * 256 + threadIdx.x;
    if (i < N_NODES) row_ptr[i] = boff[i >> 10] + tmp[i] - cnt[i];   // exclusive
}

__global__ void k_scatter(const int* __restrict__ src, const int* __restrict__ dst,
                          const int* __restrict__ row_ptr, int* __restrict__ fill,
                          int* __restrict__ col) {
    int e = blockIdx.x * 256 + threadIdx.x;
    if (e < N_EDGES) {
        int d = dst[e];
        int pos = row_ptr[d] + atomicAdd(&fill[d], 1);
        col[pos] = src[e];
    }
}

__global__ void k_dinv(const int* __restrict__ cnt, float* __restrict__ dinv) {
    int i = blockIdx.x * 256 + threadIdx.x;
    if (i < N_NODES) dinv[i] = rsqrtf((float)(cnt[i] + 1));   // +1 self-loop; always > 0
}

// ---------------- GEMM1: H1s = dinv ⊙ (X @ W1)  -> fp16 ----------------
// 64x128 tile, 256 threads, each thread 4x8 micro-tile, BK=16, A transposed in LDS.

__global__ __launch_bounds__(256) void k_gemm1(const float* __restrict__ X,
                                               const float* __restrict__ W,
                                               const float* __restrict__ dinv,
                                               __half* __restrict__ H1s) {
    __shared__ __align__(16) float As[16][68];    // [k][m], padded
    __shared__ __align__(16) float Bs[16][132];   // [k][n], padded
    const int tid = threadIdx.x;
    const int tx = tid & 15;    // col group -> 8 cols
    const int ty = tid >> 4;    // row group -> 4 rows
    const int row0 = blockIdx.x * 64;

    float acc[4][8];
    #pragma unroll
    for (int r = 0; r < 4; r++)
        #pragma unroll
        for (int c = 0; c < 8; c++) acc[r][c] = 0.f;

    const int lr = tid >> 2;          // 0..63 : A load row
    const int lk = (tid & 3) * 4;     // k quad

    for (int k0 = 0; k0 < IN_DIM; k0 += 16) {
        float4 a = make_float4(0.f, 0.f, 0.f, 0.f);
        int gr = row0 + lr;
        if (gr < N_NODES) a = *(const float4*)&X[(long)gr * IN_DIM + k0 + lk];
        As[lk + 0][lr] = a.x; As[lk + 1][lr] = a.y; As[lk + 2][lr] = a.z; As[lk + 3][lr] = a.w;
        {
            int idx = tid;
            int kk = idx >> 5, c4 = (idx & 31) * 4;
            *(float4*)&Bs[kk][c4] = *(const float4*)&W[(k0 + kk) * HIDDEN + c4];
            idx = tid + 256;
            kk = idx >> 5; c4 = (idx & 31) * 4;
            *(float4*)&Bs[kk][c4] = *(const float4*)&W[(k0 + kk) * HIDDEN + c4];
        }
        __syncthreads();
        #pragma unroll
        for (int kk = 0; kk < 16; kk++) {
            float4 av = *(const float4*)&As[kk][ty * 4];
            float4 b0 = *(const float4*)&Bs[kk][tx * 8];
            float4 b1 = *(const float4*)&Bs[kk][tx * 8 + 4];
            float a_[4] = {av.x, av.y, av.z, av.w};
            float b_[8] = {b0.x, b0.y, b0.z, b0.w, b1.x, b1.y, b1.z, b1.w};
            #pragma unroll
            for (int r = 0; r < 4; r++)
                #pragma unroll
                for (int c = 0; c < 8; c++) acc[r][c] += a_[r] * b_[c];
        }
        __syncthreads();
    }
    #pragma unroll
    for (int r = 0; r < 4; r++) {
        int gr = row0 + ty * 4 + r;
        if (gr < N_NODES) {
            float dd = dinv[gr];
            union { float4 v; __half2 h[4]; } u;
            u.h[0] = __halves2half2(__float2half_rn(dd * acc[r][0]), __float2half_rn(dd * acc[r][1]));
            u.h[1] = __halves2half2(__float2half_rn(dd * acc[r][2]), __float2half_rn(dd * acc[r][3]));
            u.h[2] = __halves2half2(__float2half_rn(dd * acc[r][4]), __float2half_rn(dd * acc[r][5]));
            u.h[3] = __halves2half2(__float2half_rn(dd * acc[r][6]), __float2half_rn(dd * acc[r][7]));
            *(float4*)&H1s[(long)gr * HIDDEN + tx * 8] = u.v;
        }
    }
}

// ---------------- Aggregation 1 (+bias+ReLU) -> fp16 H1a ----------------
// one wave per node, 2 features/lane; pure gather-sum (dinv pre-applied).

__global__ __launch_bounds__(256) void k_agg1(const __half* __restrict__ H1s,
                                              const int* __restrict__ row_ptr,
                                              const int* __restrict__ col,
                                              const float* __restrict__ dinv,
                                              const float* __restrict__ b1,
                                              __half* __restrict__ H1a) {
    int d = blockIdx.x * 4 + (threadIdx.x >> 6);
    int lane = threadIdx.x & 63;
    int e0 = row_ptr[d], e1 = row_ptr[d + 1];
    const __half2* base = (const __half2*)H1s;   // row stride 64 half2
    float ax = 0.f, ay = 0.f;
    int e = e0;
    for (; e + 3 < e1; e += 4) {
        int s0 = col[e], s1 = col[e + 1], s2 = col[e + 2], s3 = col[e + 3];
        __half2 h0 = base[(long)s0 * 64 + lane];
        __half2 h1 = base[(long)s1 * 64 + lane];
        __half2 h2 = base[(long)s2 * 64 + lane];
        __half2 h3 = base[(long)s3 * 64 + lane];
        float2 f0 = __half22float2(h0), f1 = __half22float2(h1);
        float2 f2 = __half22float2(h2), f3 = __half22float2(h3);
        ax += f0.x + f1.x + f2.x + f3.x;
        ay += f0.y + f1.y + f2.y + f3.y;
    }
    for (; e < e1; e++) {
        int s = col[e];
        float2 f = __half22float2(base[(long)s * 64 + lane]);
        ax += f.x; ay += f.y;
    }
    // self-loop term: + dd*H1[d] == + H1s[d]
    float2 fs = __half22float2(base[(long)d * 64 + lane]);
    ax += fs.x; ay += fs.y;
    float dd = dinv[d];
    float2 bb = ((const float2*)b1)[lane];
    float ox = fmaxf(dd * ax + bb.x, 0.f);
    float oy = fmaxf(dd * ay + bb.y, 0.f);
    ((__half2*)H1a)[(long)d * 64 + lane] = __halves2half2(__float2half_rn(ox), __float2half_rn(oy));
}

// ---------------- GEMM2: H2s = dinv ⊙ (H1a @ W2) -> fp16, W2 in LDS ----------------

__global__ __launch_bounds__(256) void k_gemm2(const __half* __restrict__ H1a,
                                               const float* __restrict__ W2,
                                               const float* __restrict__ dinv,
                                               __half* __restrict__ H2s) {
    __shared__ float Ws[HIDDEN * NCLS];   // 20 KB
    for (int i = threadIdx.x; i < HIDDEN * NCLS; i += 256) Ws[i] = W2[i];
    __syncthreads();
    long gid = (long)blockIdx.x * 256 + threadIdx.x;
    if (gid >= (long)N_NODES * NCLS) return;
    int row = (int)(gid / NCLS);
    int c   = (int)(gid - (long)row * NCLS);
    const float4* hrow4 = (const float4*)&H1a[(long)row * HIDDEN];  // 16 x (8 halfs)
    float acc = 0.f;
    #pragma unroll
    for (int k8 = 0; k8 < HIDDEN / 8; k8++) {
        union { float4 v; __half2 h[4]; } u;
        u.v = hrow4[k8];
        float2 f0 = __half22float2(u.h[0]), f1 = __half22float2(u.h[1]);
        float2 f2 = __half22float2(u.h[2]), f3 = __half22float2(u.h[3]);
        int kb = k8 * 8;
        acc += f0.x * Ws[(kb + 0) * NCLS + c];
        acc += f0.y * Ws[(kb + 1) * NCLS + c];
        acc += f1.x * Ws[(kb + 2) * NCLS + c];
        acc += f1.y * Ws[(kb + 3) * NCLS + c];
        acc += f2.x * Ws[(kb + 4) * NCLS + c];
        acc += f2.y * Ws[(kb + 5) * NCLS + c];
        acc += f3.x * Ws[(kb + 6) * NCLS + c];
        acc += f3.y * Ws[(kb + 7) * NCLS + c];
    }
    H2s[gid] = __float2half_rn(dinv[row] * acc);
}

// ---------------- Aggregation 2 (+bias) -> fp32 out ----------------

__global__ __launch_bounds__(256) void k_agg2(const __half* __restrict__ H2s,
                                              const int* __restrict__ row_ptr,
                                              const int* __restrict__ col,
                                              const float* __restrict__ dinv,
                                              const float* __restrict__ b2,
                                              float* __restrict__ out) {
    int d = blockIdx.x * 4 + (threadIdx.x >> 6);   // one wave per node
    int c = threadIdx.x & 63;
    if (c >= NCLS) return;
    int e0 = row_ptr[d], e1 = row_ptr[d + 1];
    float acc = 0.f;
    int e = e0;
    for (; e + 3 < e1; e += 4) {
        int s0 = col[e], s1 = col[e + 1], s2 = col[e + 2], s3 = col[e + 3];
        float v0 = __half2float(H2s[(long)s0 * NCLS + c]);
        float v1 = __half2float(H2s[(long)s1 * NCLS + c]);
        float v2 = __half2float(H2s[(long)s2 * NCLS + c]);
        float v3 = __half2float(H2s[(long)s3 * NCLS + c]);
        acc += v0 + v1 + v2 + v3;
    }
    for (; e < e1; e++) {
        acc += __half2float(H2s[(long)col[e] * NCLS + c]);
    }
    acc += __half2float(H2s[(long)d * NCLS + c]);   // self-loop (pre-scaled)
    out[(long)d * NCLS + c] = dinv[d] * acc + b2[c];
}

// ---------------- launch ----------------

extern "C" void kernel_launch(void* const* d_in, const int* in_sizes, int n_in,
                              void* d_out, int out_size, void* d_ws, size_t ws_size,
                              hipStream_t stream) {
    const float* x  = (const float*)d_in[0];
    const int*   ei = (const int*)d_in[1];
    const float* W1 = (const float*)d_in[2];
    const float* b1 = (const float*)d_in[3];
    const float* W2 = (const float*)d_in[4];
    const float* b2 = (const float*)d_in[5];
    const int* srcE = ei;
    const int* dstE = ei + N_EDGES;

    int*   cnt     = (int*)d_ws;                 // 100032
    int*   row_ptr = cnt + 100032;               // 100032
    int*   fill    = row_ptr + 100032;           // 100032
    int*   boff    = fill + 100032;              // 128
    int*   tmp     = boff + 128;                 // 100032
    int*   bsum    = tmp + 100032;               // 128
    int*   col     = bsum + 128;                 // 1600000
    float* dinv    = (float*)(col + N_EDGES);    // 100032
    __half* H1s    = (__half*)(dinv + 100032);   // 12.8M halfs (25.6 MB)
    __half* H1a    = H1s + (long)N_NODES * HIDDEN;
    __half* H2s    = H1s;                        // reuse (H1s free after agg1... but gemm2 writes while H1a read) -- keep separate:
    H2s            = H1a + (long)N_NODES * HIDDEN;

    hipMemsetAsync(cnt,  0, N_NODES * sizeof(int), stream);
    hipMemsetAsync(fill, 0, N_NODES * sizeof(int), stream);

    k_count  <<<(N_EDGES + 255) / 256, 256, 0, stream>>>(dstE, cnt);
    k_scanA  <<<SCAN_BLOCKS, 1024, 0, stream>>>(cnt, tmp, bsum);
    k_scanB  <<<1, 64, 0, stream>>>(bsum, boff, row_ptr);
    k_scanC  <<<(N_NODES + 255) / 256, 256, 0, stream>>>(tmp, cnt, boff, row_ptr);
    k_scatter<<<(N_EDGES + 255) / 256, 256, 0, stream>>>(srcE, dstE, row_ptr, fill, col);
    k_dinv   <<<(N_NODES + 255) / 256, 256, 0, stream>>>(cnt, dinv);

    k_gemm1  <<<(N_NODES + 63) / 64, 256, 0, stream>>>(x, W1, dinv, H1s);
    k_agg1   <<<N_NODES / 4, 256, 0, stream>>>(H1s, row_ptr, col, dinv, b1, H1a);
    k_gemm2  <<<(int)(((long)N_NODES * NCLS + 255) / 256), 256, 0, stream>>>(H1a, W2, dinv, H2s);
    k_agg2   <<<N_NODES / 4, 256, 0, stream>>>(H2s, row_ptr, col, dinv, b2, (float*)d_out);
}

// Round 3
// 534.565 us; speedup vs baseline: 1.3904x; 1.0824x over previous
//
#include <hip/hip_runtime.h>
#include <hip/hip_bf16.h>
#include <hip/hip_fp16.h>

#define N_NODES 100000
#define N_EDGES 1600000
#define IN_DIM 256
#define HIDDEN 128
#define NCLS 40
#define SCAN_BLOCKS 98   // ceil(100000/1024)

typedef __attribute__((ext_vector_type(8))) _Float16 half8;
typedef __attribute__((ext_vector_type(4))) float floatx4;

// ---------------- CSR build ----------------

__global__ void k_count(const int* __restrict__ dst, int* __restrict__ cnt) {
    int e = blockIdx.x * 256 + threadIdx.x;
    if (e < N_EDGES) atomicAdd(&cnt[dst[e]], 1);
}

__global__ void k_scanA(const int* __restrict__ cnt, int* __restrict__ tmp, int* __restrict__ bsum) {
    int i = blockIdx.x * 1024 + threadIdx.x;
    int v = (i < N_NODES) ? cnt[i] : 0;
    int lane = threadIdx.x & 63;
    int wid  = threadIdx.x >> 6;   // 0..15
    #pragma unroll
    for (int d = 1; d < 64; d <<= 1) {
        int u = __shfl_up(v, d, 64);
        if (lane >= d) v += u;
    }
    __shared__ int ws[16];
    if (lane == 63) ws[wid] = v;
    __syncthreads();
    if (wid == 0) {
        int s = (lane < 16) ? ws[lane] : 0;
        #pragma unroll
        for (int d = 1; d < 16; d <<= 1) {
            int u = __shfl_up(s, d, 64);
            if (lane >= d) s += u;
        }
        if (lane < 16) ws[lane] = s;
    }
    __syncthreads();
    if (wid > 0) v += ws[wid - 1];
    if (i < N_NODES) tmp[i] = v;
    if (threadIdx.x == 1023) bsum[blockIdx.x] = v;
}

__global__ void k_scanB(const int* __restrict__ bsum, int* __restrict__ boff, int* __restrict__ row_ptr) {
    if (threadIdx.x == 0 && blockIdx.x == 0) {
        int run = 0;
        for (int b = 0; b < SCAN_BLOCKS; b++) { boff[b] = run; run += bsum[b]; }
        row_ptr[N_NODES] = run;   // == N_EDGES
    }
}

__global__ void k_scanC(const int* __restrict__ tmp, const int* __restrict__ cnt,
                        const int* __restrict__ boff, int* __restrict__ row_ptr) {
    int i = blockIdx.x * 256 + threadIdx.x;
    if (i < N_NODES) row_ptr[i] = boff[i >> 10] + tmp[i] - cnt[i];   // exclusive
}

__global__ void k_scatter(const int* __restrict__ src, const int* __restrict__ dst,
                          const int* __restrict__ row_ptr, int* __restrict__ fill,
                          int* __restrict__ col) {
    int e = blockIdx.x * 256 + threadIdx.x;
    if (e < N_EDGES) {
        int d = dst[e];
        int pos = row_ptr[d] + atomicAdd(&fill[d], 1);
        col[pos] = src[e];
    }
}

__global__ void k_dinv(const int* __restrict__ cnt, float* __restrict__ dinv) {
    int i = blockIdx.x * 256 + threadIdx.x;
    if (i < N_NODES) dinv[i] = rsqrtf((float)(cnt[i] + 1));   // +1 self-loop; always > 0
}

// ---------------- W1 -> transposed fp16 (once, tiny) ----------------

__global__ __launch_bounds__(256) void k_w1t(const float* __restrict__ W1, __half* __restrict__ W1T) {
    int i = blockIdx.x * 256 + threadIdx.x;   // over 256*128
    if (i < IN_DIM * HIDDEN) {
        int k = i >> 7;     // row of W1 (K dim)
        int n = i & 127;    // col
        W1T[n * IN_DIM + k] = __float2half_rn(W1[i]);
    }
}

// ---------------- GEMM1 (MFMA f16): H1s = dinv ⊙ (X @ W1) -> fp16 ----------------
// 64(M) x 128(N) tile, K=256 in 4 chunks of 64. 4 waves, wave w -> rows [16w,16w+16).
// m92-verified fragment layouts: A[m=lane&15][k=(lane>>4)*8+j], B^T rows in LDS,
// C/D: col=lane&15, row=(lane>>4)*4+reg.

__global__ __launch_bounds__(256) void k_gemm1(const float* __restrict__ X,
                                               const __half* __restrict__ W1T,
                                               const float* __restrict__ dinv,
                                               __half* __restrict__ H1s) {
    __shared__ __align__(16) _Float16 Asm[64][72];    // pad 8 f16 (16 B) -> 2-way max
    __shared__ __align__(16) _Float16 Bsm[128][72];
    const int tid  = threadIdx.x;
    const int wave = tid >> 6;
    const int lane = tid & 63;
    const int m16  = lane & 15;
    const int kq   = lane >> 4;       // 0..3
    const int row0 = blockIdx.x * 64;

    floatx4 acc[8];
    #pragma unroll
    for (int i = 0; i < 8; i++) acc[i] = (floatx4)0.f;

    for (int kc = 0; kc < 4; kc++) {
        // stage A: 64 rows x 64 k (fp32 -> f16). 512 units of 8 f16, 2 iters.
        #pragma unroll
        for (int it = 0; it < 2; it++) {
            int u = tid + it * 256;
            int r = u >> 3, j = u & 7;
            int gr = row0 + r;
            float4 x0 = make_float4(0.f, 0.f, 0.f, 0.f), x1 = x0;
            if (gr < N_NODES) {
                const float* p = &X[(long)gr * IN_DIM + kc * 64 + j * 8];
                x0 = *(const float4*)p;
                x1 = *(const float4*)(p + 4);
            }
            half8 h;
            h[0] = (_Float16)x0.x; h[1] = (_Float16)x0.y; h[2] = (_Float16)x0.z; h[3] = (_Float16)x0.w;
            h[4] = (_Float16)x1.x; h[5] = (_Float16)x1.y; h[6] = (_Float16)x1.z; h[7] = (_Float16)x1.w;
            *(half8*)&Asm[r][j * 8] = h;
        }
        // stage B^T: 128 rows x 64 k f16. 1024 units of 8 f16, 4 iters.
        #pragma unroll
        for (int it = 0; it < 4; it++) {
            int u = tid + it * 256;
            int n = u >> 3, j = u & 7;
            float4 w = *(const float4*)&W1T[n * IN_DIM + kc * 64 + j * 8];
            *(float4*)&Bsm[n][j * 8] = w;
        }
        __syncthreads();
        #pragma unroll
        for (int ks = 0; ks < 2; ks++) {
            half8 a = *(const half8*)&Asm[wave * 16 + m16][ks * 32 + kq * 8];
            #pragma unroll
            for (int nt = 0; nt < 8; nt++) {
                half8 b = *(const half8*)&Bsm[nt * 16 + m16][ks * 32 + kq * 8];
                acc[nt] = __builtin_amdgcn_mfma_f32_16x16x32_f16(a, b, acc[nt], 0, 0, 0);
            }
        }
        __syncthreads();
    }
    // epilogue
    const int gr0 = row0 + wave * 16 + kq * 4;
    float dd[4];
    #pragma unroll
    for (int r = 0; r < 4; r++) dd[r] = (gr0 + r < N_NODES) ? dinv[gr0 + r] : 0.f;
    #pragma unroll
    for (int nt = 0; nt < 8; nt++) {
        int c = nt * 16 + m16;
        #pragma unroll
        for (int r = 0; r < 4; r++) {
            if (gr0 + r < N_NODES)
                H1s[(long)(gr0 + r) * HIDDEN + c] = __float2half_rn(dd[r] * acc[nt][r]);
        }
    }
}

// ---------------- Aggregation 1 (+bias+ReLU) -> fp16 H1a ----------------

__global__ __launch_bounds__(256) void k_agg1(const __half* __restrict__ H1s,
                                              const int* __restrict__ row_ptr,
                                              const int* __restrict__ col,
                                              const float* __restrict__ dinv,
                                              const float* __restrict__ b1,
                                              __half* __restrict__ H1a) {
    int d = blockIdx.x * 4 + (threadIdx.x >> 6);
    int lane = threadIdx.x & 63;
    int e0 = row_ptr[d], e1 = row_ptr[d + 1];
    const __half2* base = (const __half2*)H1s;   // row stride 64 half2
    float ax = 0.f, ay = 0.f;
    int e = e0;
    for (; e + 3 < e1; e += 4) {
        int s0 = col[e], s1 = col[e + 1], s2 = col[e + 2], s3 = col[e + 3];
        __half2 h0 = base[(long)s0 * 64 + lane];
        __half2 h1 = base[(long)s1 * 64 + lane];
        __half2 h2 = base[(long)s2 * 64 + lane];
        __half2 h3 = base[(long)s3 * 64 + lane];
        float2 f0 = __half22float2(h0), f1 = __half22float2(h1);
        float2 f2 = __half22float2(h2), f3 = __half22float2(h3);
        ax += f0.x + f1.x + f2.x + f3.x;
        ay += f0.y + f1.y + f2.y + f3.y;
    }
    for (; e < e1; e++) {
        int s = col[e];
        float2 f = __half22float2(base[(long)s * 64 + lane]);
        ax += f.x; ay += f.y;
    }
    float2 fs = __half22float2(base[(long)d * 64 + lane]);   // self-loop (pre-scaled)
    ax += fs.x; ay += fs.y;
    float dd = dinv[d];
    float2 bb = ((const float2*)b1)[lane];
    float ox = fmaxf(dd * ax + bb.x, 0.f);
    float oy = fmaxf(dd * ay + bb.y, 0.f);
    ((__half2*)H1a)[(long)d * 64 + lane] = __halves2half2(__float2half_rn(ox), __float2half_rn(oy));
}

// ---------------- GEMM2: H2s = dinv ⊙ (H1a @ W2) -> fp16, W2 in LDS ----------------

__global__ __launch_bounds__(256) void k_gemm2(const __half* __restrict__ H1a,
                                               const float* __restrict__ W2,
                                               const float* __restrict__ dinv,
                                               __half* __restrict__ H2s) {
    __shared__ float Ws[HIDDEN * NCLS];   // 20 KB
    for (int i = threadIdx.x; i < HIDDEN * NCLS; i += 256) Ws[i] = W2[i];
    __syncthreads();
    long gid = (long)blockIdx.x * 256 + threadIdx.x;
    if (gid >= (long)N_NODES * NCLS) return;
    int row = (int)(gid / NCLS);
    int c   = (int)(gid - (long)row * NCLS);
    const float4* hrow4 = (const float4*)&H1a[(long)row * HIDDEN];  // 16 x (8 halfs)
    float acc = 0.f;
    #pragma unroll
    for (int k8 = 0; k8 < HIDDEN / 8; k8++) {
        union { float4 v; __half2 h[4]; } u;
        u.v = hrow4[k8];
        float2 f0 = __half22float2(u.h[0]), f1 = __half22float2(u.h[1]);
        float2 f2 = __half22float2(u.h[2]), f3 = __half22float2(u.h[3]);
        int kb = k8 * 8;
        acc += f0.x * Ws[(kb + 0) * NCLS + c];
        acc += f0.y * Ws[(kb + 1) * NCLS + c];
        acc += f1.x * Ws[(kb + 2) * NCLS + c];
        acc += f1.y * Ws[(kb + 3) * NCLS + c];
        acc += f2.x * Ws[(kb + 4) * NCLS + c];
        acc += f2.y * Ws[(kb + 5) * NCLS + c];
        acc += f3.x * Ws[(kb + 6) * NCLS + c];
        acc += f3.y * Ws[(kb + 7) * NCLS + c];
    }
    H2s[gid] = __float2half_rn(dinv[row] * acc);
}

// ---------------- Aggregation 2 (+bias) -> fp32 out ----------------

__global__ __launch_bounds__(256) void k_agg2(const __half* __restrict__ H2s,
                                              const int* __restrict__ row_ptr,
                                              const int* __restrict__ col,
                                              const float* __restrict__ dinv,
                                              const float* __restrict__ b2,
                                              float* __restrict__ out) {
    int d = blockIdx.x * 4 + (threadIdx.x >> 6);   // one wave per node
    int c = threadIdx.x & 63;
    if (c >= NCLS) return;
    int e0 = row_ptr[d], e1 = row_ptr[d + 1];
    float acc = 0.f;
    int e = e0;
    for (; e + 3 < e1; e += 4) {
        int s0 = col[e], s1 = col[e + 1], s2 = col[e + 2], s3 = col[e + 3];
        float v0 = __half2float(H2s[(long)s0 * NCLS + c]);
        float v1 = __half2float(H2s[(long)s1 * NCLS + c]);
        float v2 = __half2float(H2s[(long)s2 * NCLS + c]);
        float v3 = __half2float(H2s[(long)s3 * NCLS + c]);
        acc += v0 + v1 + v2 + v3;
    }
    for (; e < e1; e++) {
        acc += __half2float(H2s[(long)col[e] * NCLS + c]);
    }
    acc += __half2float(H2s[(long)d * NCLS + c]);   // self-loop (pre-scaled)
    out[(long)d * NCLS + c] = dinv[d] * acc + b2[c];
}

// ---------------- launch ----------------

extern "C" void kernel_launch(void* const* d_in, const int* in_sizes, int n_in,
                              void* d_out, int out_size, void* d_ws, size_t ws_size,
                              hipStream_t stream) {
    const float* x  = (const float*)d_in[0];
    const int*   ei = (const int*)d_in[1];
    const float* W1 = (const float*)d_in[2];
    const float* b1 = (const float*)d_in[3];
    const float* W2 = (const float*)d_in[4];
    const float* b2 = (const float*)d_in[5];
    const int* srcE = ei;
    const int* dstE = ei + N_EDGES;

    int*   cnt     = (int*)d_ws;                 // 100032
    int*   row_ptr = cnt + 100032;               // 100032
    int*   fill    = row_ptr + 100032;           // 100032
    int*   boff    = fill + 100032;              // 128
    int*   tmp     = boff + 128;                 // 100032
    int*   bsum    = tmp + 100032;               // 128
    int*   col     = bsum + 128;                 // 1600000
    float* dinv    = (float*)(col + N_EDGES);    // 100032
    __half* H1s    = (__half*)(dinv + 100032);   // 12.8M halfs (25.6 MB)
    __half* H1a    = H1s + (long)N_NODES * HIDDEN;
    __half* H2s    = H1a + (long)N_NODES * HIDDEN;  // 4M halfs (8 MB)
    __half* W1T    = H2s + (long)N_NODES * NCLS;    // 32768 halfs (64 KB)

    hipMemsetAsync(cnt,  0, N_NODES * sizeof(int), stream);
    hipMemsetAsync(fill, 0, N_NODES * sizeof(int), stream);

    k_count  <<<(N_EDGES + 255) / 256, 256, 0, stream>>>(dstE, cnt);
    k_scanA  <<<SCAN_BLOCKS, 1024, 0, stream>>>(cnt, tmp, bsum);
    k_scanB  <<<1, 64, 0, stream>>>(bsum, boff, row_ptr);
    k_scanC  <<<(N_NODES + 255) / 256, 256, 0, stream>>>(tmp, cnt, boff, row_ptr);
    k_scatter<<<(N_EDGES + 255) / 256, 256, 0, stream>>>(srcE, dstE, row_ptr, fill, col);
    k_dinv   <<<(N_NODES + 255) / 256, 256, 0, stream>>>(cnt, dinv);
    k_w1t    <<<(IN_DIM * HIDDEN + 255) / 256, 256, 0, stream>>>(W1, W1T);

    k_gemm1  <<<(N_NODES + 63) / 64, 256, 0, stream>>>(x, W1T, dinv, H1s);
    k_agg1   <<<N_NODES / 4, 256, 0, stream>>>(H1s, row_ptr, col, dinv, b1, H1a);
    k_gemm2  <<<(int)(((long)N_NODES * NCLS + 255) / 256), 256, 0, stream>>>(H1a, W2, dinv, H2s);
    k_agg2   <<<N_NODES / 4, 256, 0, stream>>>(H2s, row_ptr, col, dinv, b2, (float*)d_out);
}

// Round 4
// 442.830 us; speedup vs baseline: 1.6785x; 1.2072x over previous
//
#include <hip/hip_runtime.h>
#include <hip/hip_bf16.h>
#include <hip/hip_fp16.h>

#define N_NODES 100000
#define N_EDGES 1600000
#define IN_DIM 256
#define HIDDEN 128
#define NCLS 40
#define SCAN_BLOCKS 98   // ceil(100000/1024)

#define N_BUCKETS 256
#define NPB 391          // nodes per bucket = ceil(100000/256)
#define BCAP 8192        // bucket capacity (mean 6250, >20 sigma headroom)
#define EPT 16           // edges per thread in k_bin
#define BIN_WG 4096      // edges per workgroup in k_bin (256*16)

typedef __attribute__((ext_vector_type(8))) _Float16 half8;
typedef __attribute__((ext_vector_type(4))) float floatx4;

// ---------------- CSR build (bucketed) ----------------

// Phase 1: partition edges into 256 dst-range buckets with coalesced writes.
__global__ __launch_bounds__(256) void k_bin(const int* __restrict__ src, const int* __restrict__ dst,
                                             int* __restrict__ bfill,
                                             int* __restrict__ bsrc, int* __restrict__ bdst) {
    __shared__ int hist[N_BUCKETS];
    __shared__ int base[N_BUCKETS];
    const int t = threadIdx.x;
    hist[t] = 0;
    __syncthreads();
    const long e0 = (long)blockIdx.x * BIN_WG;
    int msrc[EPT], mdst[EPT], moff[EPT];
    #pragma unroll
    for (int i = 0; i < EPT; i++) {
        long e = e0 + t + i * 256;
        if (e < N_EDGES) {
            msrc[i] = src[e];
            mdst[i] = dst[e];
            moff[i] = atomicAdd(&hist[mdst[i] / NPB], 1);
        } else {
            mdst[i] = -1;
        }
    }
    __syncthreads();
    int h = hist[t];
    base[t] = (h > 0) ? atomicAdd(&bfill[t], h) : 0;
    __syncthreads();
    #pragma unroll
    for (int i = 0; i < EPT; i++) {
        if (mdst[i] >= 0) {
            int b = mdst[i] / NPB;
            int p = base[b] + moff[i];
            bsrc[b * BCAP + p] = msrc[i];
            bdst[b * BCAP + p] = mdst[i];
        }
    }
}

// Phase 2a: per-bucket node-degree histogram -> cnt (coalesced write, replaces k_count).
__global__ __launch_bounds__(256) void k_hist(const int* __restrict__ bfill, const int* __restrict__ bdst,
                                              int* __restrict__ cnt) {
    __shared__ int h[NPB];
    const int b = blockIdx.x;
    const int nb = b * NPB;
    const int nn = min(NPB, N_NODES - nb);
    for (int i = threadIdx.x; i < nn; i += 256) h[i] = 0;
    __syncthreads();
    const int n = bfill[b];
    for (int i = threadIdx.x; i < n; i += 256) {
        atomicAdd(&h[bdst[b * BCAP + i] - nb], 1);
    }
    __syncthreads();
    for (int i = threadIdx.x; i < nn; i += 256) cnt[nb + i] = h[i];
}

__global__ void k_scanA(const int* __restrict__ cnt, int* __restrict__ tmp, int* __restrict__ bsum) {
    int i = blockIdx.x * 1024 + threadIdx.x;
    int v = (i < N_NODES) ? cnt[i] : 0;
    int lane = threadIdx.x & 63;
    int wid  = threadIdx.x >> 6;   // 0..15
    #pragma unroll
    for (int d = 1; d < 64; d <<= 1) {
        int u = __shfl_up(v, d, 64);
        if (lane >= d) v += u;
    }
    __shared__ int ws[16];
    if (lane == 63) ws[wid] = v;
    __syncthreads();
    if (wid == 0) {
        int s = (lane < 16) ? ws[lane] : 0;
        #pragma unroll
        for (int d = 1; d < 16; d <<= 1) {
            int u = __shfl_up(s, d, 64);
            if (lane >= d) s += u;
        }
        if (lane < 16) ws[lane] = s;
    }
    __syncthreads();
    if (wid > 0) v += ws[wid - 1];
    if (i < N_NODES) tmp[i] = v;
    if (threadIdx.x == 1023) bsum[blockIdx.x] = v;
}

__global__ void k_scanB(const int* __restrict__ bsum, int* __restrict__ boff, int* __restrict__ row_ptr) {
    if (threadIdx.x == 0 && blockIdx.x == 0) {
        int run = 0;
        for (int b = 0; b < SCAN_BLOCKS; b++) { boff[b] = run; run += bsum[b]; }
        row_ptr[N_NODES] = run;   // == N_EDGES
    }
}

__global__ void k_scanC(const int* __restrict__ tmp, const int* __restrict__ cnt,
                        const int* __restrict__ boff, int* __restrict__ row_ptr) {
    int i = blockIdx.x * 256 + threadIdx.x;
    if (i < N_NODES) row_ptr[i] = boff[i >> 10] + tmp[i] - cnt[i];   // exclusive
}

// Phase 2b: per-bucket scatter, LDS fill counters, col writes stay in a ~25 KB window.
__global__ __launch_bounds__(256) void k_scatter2(const int* __restrict__ bfill,
                                                  const int* __restrict__ bsrc, const int* __restrict__ bdst,
                                                  const int* __restrict__ row_ptr, int* __restrict__ col) {
    __shared__ int f[NPB];
    const int b = blockIdx.x;
    const int nb = b * NPB;
    const int nn = min(NPB, N_NODES - nb);
    for (int i = threadIdx.x; i < nn; i += 256) f[i] = 0;
    __syncthreads();
    const int n = bfill[b];
    for (int i = threadIdx.x; i < n; i += 256) {
        int d = bdst[b * BCAP + i];
        int s = bsrc[b * BCAP + i];
        int pos = row_ptr[d] + atomicAdd(&f[d - nb], 1);
        col[pos] = s;
    }
}

__global__ void k_dinv(const int* __restrict__ cnt, float* __restrict__ dinv) {
    int i = blockIdx.x * 256 + threadIdx.x;
    if (i < N_NODES) dinv[i] = rsqrtf((float)(cnt[i] + 1));   // +1 self-loop; always > 0
}

// ---------------- W1 -> transposed fp16 (once, tiny) ----------------

__global__ __launch_bounds__(256) void k_w1t(const float* __restrict__ W1, __half* __restrict__ W1T) {
    int i = blockIdx.x * 256 + threadIdx.x;   // over 256*128
    if (i < IN_DIM * HIDDEN) {
        int k = i >> 7;     // row of W1 (K dim)
        int n = i & 127;    // col
        W1T[n * IN_DIM + k] = __float2half_rn(W1[i]);
    }
}

// ---------------- GEMM1 (MFMA f16): H1s = dinv ⊙ (X @ W1) -> fp16 ----------------

__global__ __launch_bounds__(256) void k_gemm1(const float* __restrict__ X,
                                               const __half* __restrict__ W1T,
                                               const float* __restrict__ dinv,
                                               __half* __restrict__ H1s) {
    __shared__ __align__(16) _Float16 Asm[64][72];
    __shared__ __align__(16) _Float16 Bsm[128][72];
    const int tid  = threadIdx.x;
    const int wave = tid >> 6;
    const int lane = tid & 63;
    const int m16  = lane & 15;
    const int kq   = lane >> 4;       // 0..3
    const int row0 = blockIdx.x * 64;

    floatx4 acc[8];
    #pragma unroll
    for (int i = 0; i < 8; i++) acc[i] = (floatx4)0.f;

    for (int kc = 0; kc < 4; kc++) {
        #pragma unroll
        for (int it = 0; it < 2; it++) {
            int u = tid + it * 256;
            int r = u >> 3, j = u & 7;
            int gr = row0 + r;
            float4 x0 = make_float4(0.f, 0.f, 0.f, 0.f), x1 = x0;
            if (gr < N_NODES) {
                const float* p = &X[(long)gr * IN_DIM + kc * 64 + j * 8];
                x0 = *(const float4*)p;
                x1 = *(const float4*)(p + 4);
            }
            half8 h;
            h[0] = (_Float16)x0.x; h[1] = (_Float16)x0.y; h[2] = (_Float16)x0.z; h[3] = (_Float16)x0.w;
            h[4] = (_Float16)x1.x; h[5] = (_Float16)x1.y; h[6] = (_Float16)x1.z; h[7] = (_Float16)x1.w;
            *(half8*)&Asm[r][j * 8] = h;
        }
        #pragma unroll
        for (int it = 0; it < 4; it++) {
            int u = tid + it * 256;
            int n = u >> 3, j = u & 7;
            float4 w = *(const float4*)&W1T[n * IN_DIM + kc * 64 + j * 8];
            *(float4*)&Bsm[n][j * 8] = w;
        }
        __syncthreads();
        #pragma unroll
        for (int ks = 0; ks < 2; ks++) {
            half8 a = *(const half8*)&Asm[wave * 16 + m16][ks * 32 + kq * 8];
            #pragma unroll
            for (int nt = 0; nt < 8; nt++) {
                half8 b = *(const half8*)&Bsm[nt * 16 + m16][ks * 32 + kq * 8];
                acc[nt] = __builtin_amdgcn_mfma_f32_16x16x32_f16(a, b, acc[nt], 0, 0, 0);
            }
        }
        __syncthreads();
    }
    const int gr0 = row0 + wave * 16 + kq * 4;
    float dd[4];
    #pragma unroll
    for (int r = 0; r < 4; r++) dd[r] = (gr0 + r < N_NODES) ? dinv[gr0 + r] : 0.f;
    #pragma unroll
    for (int nt = 0; nt < 8; nt++) {
        int c = nt * 16 + m16;
        #pragma unroll
        for (int r = 0; r < 4; r++) {
            if (gr0 + r < N_NODES)
                H1s[(long)(gr0 + r) * HIDDEN + c] = __float2half_rn(dd[r] * acc[nt][r]);
        }
    }
}

// ---------------- Aggregation 1 (+bias+ReLU) -> fp16 H1a ----------------

__global__ __launch_bounds__(256) void k_agg1(const __half* __restrict__ H1s,
                                              const int* __restrict__ row_ptr,
                                              const int* __restrict__ col,
                                              const float* __restrict__ dinv,
                                              const float* __restrict__ b1,
                                              __half* __restrict__ H1a) {
    int d = blockIdx.x * 4 + (threadIdx.x >> 6);
    int lane = threadIdx.x & 63;
    int e0 = row_ptr[d], e1 = row_ptr[d + 1];
    const __half2* base = (const __half2*)H1s;   // row stride 64 half2
    float ax = 0.f, ay = 0.f;
    int e = e0;
    for (; e + 3 < e1; e += 4) {
        int s0 = col[e], s1 = col[e + 1], s2 = col[e + 2], s3 = col[e + 3];
        __half2 h0 = base[(long)s0 * 64 + lane];
        __half2 h1 = base[(long)s1 * 64 + lane];
        __half2 h2 = base[(long)s2 * 64 + lane];
        __half2 h3 = base[(long)s3 * 64 + lane];
        float2 f0 = __half22float2(h0), f1 = __half22float2(h1);
        float2 f2 = __half22float2(h2), f3 = __half22float2(h3);
        ax += f0.x + f1.x + f2.x + f3.x;
        ay += f0.y + f1.y + f2.y + f3.y;
    }
    for (; e < e1; e++) {
        int s = col[e];
        float2 f = __half22float2(base[(long)s * 64 + lane]);
        ax += f.x; ay += f.y;
    }
    float2 fs = __half22float2(base[(long)d * 64 + lane]);   // self-loop (pre-scaled)
    ax += fs.x; ay += fs.y;
    float dd = dinv[d];
    float2 bb = ((const float2*)b1)[lane];
    float ox = fmaxf(dd * ax + bb.x, 0.f);
    float oy = fmaxf(dd * ay + bb.y, 0.f);
    ((__half2*)H1a)[(long)d * 64 + lane] = __halves2half2(__float2half_rn(ox), __float2half_rn(oy));
}

// ---------------- GEMM2: H2s = dinv ⊙ (H1a @ W2) -> fp16, W2 in LDS ----------------

__global__ __launch_bounds__(256) void k_gemm2(const __half* __restrict__ H1a,
                                               const float* __restrict__ W2,
                                               const float* __restrict__ dinv,
                                               __half* __restrict__ H2s) {
    __shared__ float Ws[HIDDEN * NCLS];   // 20 KB
    for (int i = threadIdx.x; i < HIDDEN * NCLS; i += 256) Ws[i] = W2[i];
    __syncthreads();
    long gid = (long)blockIdx.x * 256 + threadIdx.x;
    if (gid >= (long)N_NODES * NCLS) return;
    int row = (int)(gid / NCLS);
    int c   = (int)(gid - (long)row * NCLS);
    const float4* hrow4 = (const float4*)&H1a[(long)row * HIDDEN];
    float acc = 0.f;
    #pragma unroll
    for (int k8 = 0; k8 < HIDDEN / 8; k8++) {
        union { float4 v; __half2 h[4]; } u;
        u.v = hrow4[k8];
        float2 f0 = __half22float2(u.h[0]), f1 = __half22float2(u.h[1]);
        float2 f2 = __half22float2(u.h[2]), f3 = __half22float2(u.h[3]);
        int kb = k8 * 8;
        acc += f0.x * Ws[(kb + 0) * NCLS + c];
        acc += f0.y * Ws[(kb + 1) * NCLS + c];
        acc += f1.x * Ws[(kb + 2) * NCLS + c];
        acc += f1.y * Ws[(kb + 3) * NCLS + c];
        acc += f2.x * Ws[(kb + 4) * NCLS + c];
        acc += f2.y * Ws[(kb + 5) * NCLS + c];
        acc += f3.x * Ws[(kb + 6) * NCLS + c];
        acc += f3.y * Ws[(kb + 7) * NCLS + c];
    }
    H2s[gid] = __float2half_rn(dinv[row] * acc);
}

// ---------------- Aggregation 2 (+bias) -> fp32 out ----------------

__global__ __launch_bounds__(256) void k_agg2(const __half* __restrict__ H2s,
                                              const int* __restrict__ row_ptr,
                                              const int* __restrict__ col,
                                              const float* __restrict__ dinv,
                                              const float* __restrict__ b2,
                                              float* __restrict__ out) {
    int d = blockIdx.x * 4 + (threadIdx.x >> 6);   // one wave per node
    int c = threadIdx.x & 63;
    if (c >= NCLS) return;
    int e0 = row_ptr[d], e1 = row_ptr[d + 1];
    float acc = 0.f;
    int e = e0;
    for (; e + 3 < e1; e += 4) {
        int s0 = col[e], s1 = col[e + 1], s2 = col[e + 2], s3 = col[e + 3];
        float v0 = __half2float(H2s[(long)s0 * NCLS + c]);
        float v1 = __half2float(H2s[(long)s1 * NCLS + c]);
        float v2 = __half2float(H2s[(long)s2 * NCLS + c]);
        float v3 = __half2float(H2s[(long)s3 * NCLS + c]);
        acc += v0 + v1 + v2 + v3;
    }
    for (; e < e1; e++) {
        acc += __half2float(H2s[(long)col[e] * NCLS + c]);
    }
    acc += __half2float(H2s[(long)d * NCLS + c]);   // self-loop (pre-scaled)
    out[(long)d * NCLS + c] = dinv[d] * acc + b2[c];
}

// ---------------- launch ----------------

extern "C" void kernel_launch(void* const* d_in, const int* in_sizes, int n_in,
                              void* d_out, int out_size, void* d_ws, size_t ws_size,
                              hipStream_t stream) {
    const float* x  = (const float*)d_in[0];
    const int*   ei = (const int*)d_in[1];
    const float* W1 = (const float*)d_in[2];
    const float* b1 = (const float*)d_in[3];
    const float* W2 = (const float*)d_in[4];
    const float* b2 = (const float*)d_in[5];
    const int* srcE = ei;
    const int* dstE = ei + N_EDGES;

    int*   cnt     = (int*)d_ws;                 // 100032
    int*   row_ptr = cnt + 100032;               // 100032
    int*   boff    = row_ptr + 100032;           // 128
    int*   tmp     = boff + 128;                 // 100032
    int*   bsum    = tmp + 100032;               // 128
    int*   bfill   = bsum + 128;                 // 256
    int*   col     = bfill + 256;                // 1600000
    float* dinv    = (float*)(col + N_EDGES);    // 100032
    __half* H1s    = (__half*)(dinv + 100032);   // 12.8M halfs (25.6 MB)
    __half* H1a    = H1s + (long)N_NODES * HIDDEN;
    __half* H2s    = H1a + (long)N_NODES * HIDDEN;  // 4M halfs (8 MB)
    __half* W1T    = H2s + (long)N_NODES * NCLS;    // 32768 halfs (64 KB)
    // bucket arrays alias H1s (dead before k_gemm1 writes H1s)
    int*   bsrc    = (int*)H1s;                  // 2M ints (8 MB)
    int*   bdst    = bsrc + N_BUCKETS * BCAP;    // 2M ints (8 MB)

    hipMemsetAsync(bfill, 0, N_BUCKETS * sizeof(int), stream);

    k_bin     <<<(N_EDGES + BIN_WG - 1) / BIN_WG, 256, 0, stream>>>(srcE, dstE, bfill, bsrc, bdst);
    k_hist    <<<N_BUCKETS, 256, 0, stream>>>(bfill, bdst, cnt);
    k_scanA   <<<SCAN_BLOCKS, 1024, 0, stream>>>(cnt, tmp, bsum);
    k_scanB   <<<1, 64, 0, stream>>>(bsum, boff, row_ptr);
    k_scanC   <<<(N_NODES + 255) / 256, 256, 0, stream>>>(tmp, cnt, boff, row_ptr);
    k_scatter2<<<N_BUCKETS, 256, 0, stream>>>(bfill, bsrc, bdst, row_ptr, col);
    k_dinv    <<<(N_NODES + 255) / 256, 256, 0, stream>>>(cnt, dinv);
    k_w1t     <<<(IN_DIM * HIDDEN + 255) / 256, 256, 0, stream>>>(W1, W1T);

    k_gemm1   <<<(N_NODES + 63) / 64, 256, 0, stream>>>(x, W1T, dinv, H1s);
    k_agg1    <<<N_NODES / 4, 256, 0, stream>>>(H1s, row_ptr, col, dinv, b1, H1a);
    k_gemm2   <<<(int)(((long)N_NODES * NCLS + 255) / 256), 256, 0, stream>>>(H1a, W2, dinv, H2s);
    k_agg2    <<<N_NODES / 4, 256, 0, stream>>>(H2s, row_ptr, col, dinv, b2, (float*)d_out);
}